// Round 1
// baseline (1534.937 us; speedup 1.0000x reference)
//
#include <hip/hip_runtime.h>
#include <cstdint>
#include <cstddef>

// Sinkhorn OT loss, B=4096, D=512, fp32 throughout (correctness-first baseline).
// ws layout (floats): K[4096*4096] | KT[4096*4096] | Xs[4096] | Ys[4096] | u[4096] | v[4096]
// total ~128.1 MB.

#define N_B 4096
#define N_D 512
#define REG_ 0.05f
#define EPS_ 1e-9f
#define COST_CAP_ 1000.0f

__device__ __forceinline__ float wave_reduce_sum(float x) {
#pragma unroll
  for (int off = 32; off > 0; off >>= 1) x += __shfl_down(x, off);
  return x;
}

// One wave per row: out[row] = sum(X[row][:]^2)
__global__ __launch_bounds__(256) void rownorm_kernel(const float* __restrict__ X,
                                                      float* __restrict__ out) {
  int row = blockIdx.x * 4 + (threadIdx.x >> 6);
  int lane = threadIdx.x & 63;
  const float4* Xr = (const float4*)(X + (size_t)row * N_D);
  float acc = 0.f;
#pragma unroll
  for (int k = lane; k < N_D / 4; k += 64) {
    float4 a = Xr[k];
    acc += a.x * a.x + a.y * a.y + a.z * a.z + a.w * a.w;
  }
  acc = wave_reduce_sum(acc);
  if (lane == 0) out[row] = acc;
}

__global__ __launch_bounds__(256) void init_v_kernel(float* __restrict__ v) {
  int i = blockIdx.x * 256 + threadIdx.x;
  if (i < N_B) v[i] = 1.0f;
}

// Tiled fp32 matmul: cost[i][j] = max(0, Xs[i]+Ys[j]-2*dot(X_i,Y_j));
// K = exp(-min(cost,1000)/REG). Writes K row-major AND KT row-major (coalesced
// float4 both ways via the 4x4 register tile).
__global__ __launch_bounds__(256) void costK_kernel(const float* __restrict__ X,
                                                    const float* __restrict__ Y,
                                                    const float* __restrict__ Xs,
                                                    const float* __restrict__ Ys,
                                                    float* __restrict__ Km,
                                                    float* __restrict__ KTm) {
  __shared__ float As[64][33];  // +1 pad: bank-conflict-free column reads
  __shared__ float Bs[64][33];
  const int tid = threadIdx.x;
  const int tx = tid & 15, ty = tid >> 4;
  const int row0 = blockIdx.y * 64, col0 = blockIdx.x * 64;
  float acc[4][4] = {};

  for (int k0 = 0; k0 < N_D; k0 += 32) {
    // 64 rows x 32 cols = 512 float4 loads, 2 per thread
#pragma unroll
    for (int l = tid; l < 64 * 32 / 4; l += 256) {
      int r = l >> 3;
      int c = (l & 7) * 4;
      float4 fa = *(const float4*)&X[(size_t)(row0 + r) * N_D + k0 + c];
      As[r][c] = fa.x; As[r][c + 1] = fa.y; As[r][c + 2] = fa.z; As[r][c + 3] = fa.w;
      float4 fb = *(const float4*)&Y[(size_t)(col0 + r) * N_D + k0 + c];
      Bs[r][c] = fb.x; Bs[r][c + 1] = fb.y; Bs[r][c + 2] = fb.z; Bs[r][c + 3] = fb.w;
    }
    __syncthreads();
#pragma unroll 8
    for (int kk = 0; kk < 32; ++kk) {
      float a[4], b[4];
#pragma unroll
      for (int i = 0; i < 4; ++i) a[i] = As[ty * 4 + i][kk];
#pragma unroll
      for (int j = 0; j < 4; ++j) b[j] = Bs[tx * 4 + j][kk];
#pragma unroll
      for (int i = 0; i < 4; ++i)
#pragma unroll
        for (int j = 0; j < 4; ++j) acc[i][j] += a[i] * b[j];
    }
    __syncthreads();
  }

  float kv[4][4];
#pragma unroll
  for (int i = 0; i < 4; ++i) {
    int r = row0 + ty * 4 + i;
    float xs = Xs[r];
#pragma unroll
    for (int j = 0; j < 4; ++j) {
      int c = col0 + tx * 4 + j;
      float cost = fmaxf(xs + Ys[c] - 2.0f * acc[i][j], 0.0f);
      kv[i][j] = expf(-fminf(cost, COST_CAP_) * (1.0f / REG_));
    }
  }
#pragma unroll
  for (int i = 0; i < 4; ++i) {
    int r = row0 + ty * 4 + i;
    *(float4*)&Km[(size_t)r * N_B + col0 + tx * 4] =
        make_float4(kv[i][0], kv[i][1], kv[i][2], kv[i][3]);
  }
#pragma unroll
  for (int j = 0; j < 4; ++j) {
    int c = col0 + tx * 4 + j;
    *(float4*)&KTm[(size_t)c * N_B + row0 + ty * 4] =
        make_float4(kv[0][j], kv[1][j], kv[2][j], kv[3][j]);
  }
}

// One wave per row: out[row] = scale / (dot(M[row][:], x) + EPS)
__global__ __launch_bounds__(256) void matvec_kernel(const float* __restrict__ M,
                                                     const float* __restrict__ x,
                                                     float* __restrict__ out, float scale) {
  int row = blockIdx.x * 4 + (threadIdx.x >> 6);
  int lane = threadIdx.x & 63;
  const float4* Mr = (const float4*)(M + (size_t)row * N_B);
  const float4* xv = (const float4*)x;
  float acc = 0.f;
#pragma unroll 4
  for (int k = lane; k < N_B / 4; k += 64) {
    float4 m = Mr[k];
    float4 vv = xv[k];
    acc += m.x * vv.x + m.y * vv.y + m.z * vv.z + m.w * vv.w;
  }
  acc = wave_reduce_sum(acc);
  if (lane == 0) out[row] = scale / (acc + EPS_);
}

// loss = sum_ij u_i * K_ij * v_j * cost_ij, with cost_ij = -REG*log(K_ij)
// (exact inverse of the K construction; cost < COST_CAP everywhere here).
__global__ __launch_bounds__(256) void loss_kernel(const float* __restrict__ Km,
                                                   const float* __restrict__ u,
                                                   const float* __restrict__ v,
                                                   float* __restrict__ out) {
  __shared__ float wpart[4];
  const size_t NN = (size_t)N_B * N_B;
  size_t stride = (size_t)gridDim.x * 256;
  float acc = 0.f;
  for (size_t idx = (size_t)blockIdx.x * 256 + threadIdx.x; idx < NN; idx += stride) {
    int i = (int)(idx >> 12);
    int j = (int)(idx & (N_B - 1));
    float k = Km[idx];
    float c = -REG_ * logf(k);
    acc += u[i] * v[j] * k * c;
  }
  acc = wave_reduce_sum(acc);
  int wid = threadIdx.x >> 6, lane = threadIdx.x & 63;
  if (lane == 0) wpart[wid] = acc;
  __syncthreads();
  if (threadIdx.x == 0) {
    atomicAdd(out, wpart[0] + wpart[1] + wpart[2] + wpart[3]);
  }
}

extern "C" void kernel_launch(void* const* d_in, const int* in_sizes, int n_in,
                              void* d_out, int out_size, void* d_ws, size_t ws_size,
                              hipStream_t stream) {
  const float* X = (const float*)d_in[0];  // audio_features [4096,512]
  const float* Y = (const float*)d_in[1];  // text_features  [4096,512]
  float* out = (float*)d_out;
  float* ws = (float*)d_ws;

  const size_t NN = (size_t)N_B * N_B;
  float* Km = ws;
  float* KTm = ws + NN;
  float* Xs = ws + 2 * NN;
  float* Ys = Xs + N_B;
  float* u = Ys + N_B;
  float* v = u + N_B;

  hipMemsetAsync(d_out, 0, sizeof(float), stream);

  rownorm_kernel<<<N_B / 4, 256, 0, stream>>>(X, Xs);
  rownorm_kernel<<<N_B / 4, 256, 0, stream>>>(Y, Ys);
  init_v_kernel<<<N_B / 256, 256, 0, stream>>>(v);

  costK_kernel<<<dim3(64, 64), 256, 0, stream>>>(X, Y, Xs, Ys, Km, KTm);

  const float inv_n = 1.0f / (float)N_B;  // a = b = 1/4096 (exact in fp32)
  for (int it = 0; it < 50; ++it) {
    matvec_kernel<<<N_B / 4, 256, 0, stream>>>(Km, v, u, inv_n);   // u = a/(K v + eps)
    matvec_kernel<<<N_B / 4, 256, 0, stream>>>(KTm, u, v, inv_n);  // v = b/(K^T u + eps)
  }

  loss_kernel<<<2048, 256, 0, stream>>>(Km, u, v, out);
}

// Round 2
// 836.042 us; speedup vs baseline: 1.8360x; 1.8360x over previous
//
#include <hip/hip_runtime.h>
#include <cstdint>
#include <cstddef>

// Sinkhorn OT loss, B=4096, D=512.
// K stored bf16 (32MB) + KT bf16 (32MB); cost matmul via bf16 MFMA with
// hi/lo fp32-emulation split (K_expanded = 1536 = hi|lo|hi pairing).
// ws layout (bytes):
//   Km   [0,   32MB)   bf16 K
//   KTm  [32MB,64MB)   bf16 K^T
//   Xe   [64MB, +12.6MB)  expanded X (hi|lo|hi), bf16 [4096][1536]
//   Ye   (Xe end, +12.6MB) expanded Y (hi|hi|lo)
//   Xs,Ys,u,v: 4x 16KB floats after that.

#define N_B 4096
#define N_D 512
#define KE  1536
#define REG_ 0.05f
#define EPS_ 1e-9f

typedef __attribute__((ext_vector_type(8))) short bs8;    // 8 bf16 as shorts (MFMA frag)
typedef __attribute__((ext_vector_type(8))) unsigned short us8;
typedef __attribute__((ext_vector_type(4))) float f32x4;

__device__ __forceinline__ float bf2f(unsigned short u) {
  union { uint32_t i; float f; } x; x.i = ((uint32_t)u) << 16; return x.f;
}
__device__ __forceinline__ unsigned short f2bf(float f) {
  union { float f; uint32_t i; } x; x.f = f;
  uint32_t r = (x.i + 0x7FFFu + ((x.i >> 16) & 1u)) >> 16;
  return (unsigned short)r;
}

__device__ __forceinline__ float wave_reduce_sum(float x) {
#pragma unroll
  for (int off = 32; off > 0; off >>= 1) x += __shfl_down(x, off);
  return x;
}

// Split X,Y into bf16 hi/lo and build expanded operands:
// Xe = [hi | lo | hi], Ye = [hi | hi | lo]  => sum over KE gives
// hi*hi + lo*hi + hi*lo  (lo*lo term ~2^-34 rel, negligible).
__global__ __launch_bounds__(256) void prep_kernel(const float* __restrict__ X,
                                                   const float* __restrict__ Y,
                                                   unsigned short* __restrict__ Xe,
                                                   unsigned short* __restrict__ Ye) {
  int idx = blockIdx.x * 256 + threadIdx.x;  // 0 .. 4096*512-1
  int row = idx >> 9, col = idx & 511;
  size_t base = (size_t)row * KE + col;
  float x = X[idx];
  unsigned short xh = f2bf(x);
  unsigned short xl = f2bf(x - bf2f(xh));
  Xe[base] = xh; Xe[base + 512] = xl; Xe[base + 1024] = xh;
  float y = Y[idx];
  unsigned short yh = f2bf(y);
  unsigned short yl = f2bf(y - bf2f(yh));
  Ye[base] = yh; Ye[base + 512] = yh; Ye[base + 1024] = yl;
}

// One wave per row: out[row] = sum(X[row][:]^2), exact fp32.
__global__ __launch_bounds__(256) void rownorm_kernel(const float* __restrict__ X,
                                                      float* __restrict__ out) {
  int row = blockIdx.x * 4 + (threadIdx.x >> 6);
  int lane = threadIdx.x & 63;
  const float4* Xr = (const float4*)(X + (size_t)row * N_D);
  float acc = 0.f;
#pragma unroll
  for (int k = lane; k < N_D / 4; k += 64) {
    float4 a = Xr[k];
    acc += a.x * a.x + a.y * a.y + a.z * a.z + a.w * a.w;
  }
  acc = wave_reduce_sum(acc);
  if (lane == 0) out[row] = acc;
}

__global__ __launch_bounds__(256) void init_v_kernel(float* __restrict__ v) {
  int i = blockIdx.x * 256 + threadIdx.x;
  if (i < N_B) v[i] = 1.0f;
}

// 128x128-tile MFMA GEMM (m97 structure): C = Xe . Ye^T over KE=1536,
// epilogue: cost = max(0, Xs+Ys-2C), K = exp(-min(cost,1000)/REG) -> bf16.
__global__ __launch_bounds__(256) void gemm_costK(const unsigned short* __restrict__ Xe,
                                                  const unsigned short* __restrict__ Ye,
                                                  const float* __restrict__ Xs,
                                                  const float* __restrict__ Ys,
                                                  unsigned short* __restrict__ Km) {
  __shared__ unsigned short As[128 * 32];
  __shared__ unsigned short Bs[128 * 32];
  const int tid = threadIdx.x;
  const int lane = tid & 63, w = tid >> 6;
  const int wr = w >> 1, wc = w & 1;
  const int row0 = blockIdx.y * 128, col0 = blockIdx.x * 128;

  f32x4 acc[4][4];
#pragma unroll
  for (int i = 0; i < 4; ++i)
#pragma unroll
    for (int j = 0; j < 4; ++j) acc[i][j] = (f32x4)(0.0f);

  // staging coords: chunk c covers LDS bytes [c*4096 + tid*16)
  const int srow = tid >> 2;          // + c*64
  const int scol = (tid & 3) * 8;     // bf16 elems

  for (int k0 = 0; k0 < KE; k0 += 32) {
#pragma unroll
    for (int c = 0; c < 2; ++c) {
      int r = srow + c * 64;
      const unsigned short* ga = Xe + (size_t)(row0 + r) * KE + k0 + scol;
      const unsigned short* gb = Ye + (size_t)(col0 + r) * KE + k0 + scol;
      char* la = (char*)As + c * 4096 + w * 1024;
      char* lb = (char*)Bs + c * 4096 + w * 1024;
      __builtin_amdgcn_global_load_lds((const __attribute__((address_space(1))) void*)ga,
                                       (__attribute__((address_space(3))) void*)la, 16, 0, 0);
      __builtin_amdgcn_global_load_lds((const __attribute__((address_space(1))) void*)gb,
                                       (__attribute__((address_space(3))) void*)lb, 16, 0, 0);
    }
    __syncthreads();
    bs8 af[4], bfr[4];
#pragma unroll
    for (int f = 0; f < 4; ++f) {
      af[f]  = *(const bs8*)&As[(wr * 64 + f * 16 + (lane & 15)) * 32 + (lane >> 4) * 8];
      bfr[f] = *(const bs8*)&Bs[(wc * 64 + f * 16 + (lane & 15)) * 32 + (lane >> 4) * 8];
    }
#pragma unroll
    for (int i = 0; i < 4; ++i)
#pragma unroll
      for (int j = 0; j < 4; ++j)
        acc[i][j] = __builtin_amdgcn_mfma_f32_16x16x32_bf16(af[i], bfr[j], acc[i][j], 0, 0, 0);
    __syncthreads();
  }

  // epilogue: C/D layout col=lane&15, row=(lane>>4)*4+q  [m89/m91 verified]
#pragma unroll
  for (int j = 0; j < 4; ++j) {
    int col = col0 + wc * 64 + j * 16 + (lane & 15);
    float ys = Ys[col];
#pragma unroll
    for (int i = 0; i < 4; ++i) {
#pragma unroll
      for (int q = 0; q < 4; ++q) {
        int row = row0 + wr * 64 + i * 16 + (lane >> 4) * 4 + q;
        float cost = fmaxf(Xs[row] + ys - 2.0f * acc[i][j][q], 0.0f);
        float kf = expf(-fminf(cost, 1000.0f) * (1.0f / REG_));
        Km[(size_t)row * N_B + col] = f2bf(kf);
      }
    }
  }
}

// 64x64 LDS-tiled bf16 transpose: KT[c][r] = K[r][c].
__global__ __launch_bounds__(256) void transpose_bf16(const unsigned short* __restrict__ in,
                                                      unsigned short* __restrict__ out) {
  __shared__ unsigned short t[64][66];
  const int tid = threadIdx.x;
  const int r0 = blockIdx.y * 64, c0 = blockIdx.x * 64;
#pragma unroll
  for (int c = 0; c < 2; ++c) {
    int lin = c * 2048 + tid * 8;
    int r = lin >> 6, col = lin & 63;
    us8 m = *(const us8*)&in[(size_t)(r0 + r) * N_B + c0 + col];
#pragma unroll
    for (int k = 0; k < 8; ++k) t[r][col + k] = m[k];
  }
  __syncthreads();
#pragma unroll
  for (int c = 0; c < 2; ++c) {
    int lin = c * 2048 + tid * 8;
    int j = lin >> 6, i0 = lin & 63;
    us8 m;
#pragma unroll
    for (int k = 0; k < 8; ++k) m[k] = t[i0 + k][j];
    *(us8*)&out[(size_t)(c0 + j) * N_B + r0 + i0] = m;
  }
}

// One wave per row: out[row] = scale / (dot(M_bf16[row][:], x) + EPS)
__global__ __launch_bounds__(256) void matvec_bf16(const unsigned short* __restrict__ M,
                                                   const float* __restrict__ x,
                                                   float* __restrict__ out, float scale) {
  int row = blockIdx.x * 4 + (threadIdx.x >> 6);
  int lane = threadIdx.x & 63;
  const us8* Mr = (const us8*)(M + (size_t)row * N_B);
  const f32x4* xv = (const f32x4*)x;
  float acc = 0.f;
#pragma unroll
  for (int it = 0; it < 8; ++it) {
    int c = it * 64 + lane;
    us8 m = Mr[c];
    f32x4 v0 = xv[2 * c], v1 = xv[2 * c + 1];
    acc += bf2f(m[0]) * v0[0] + bf2f(m[1]) * v0[1] + bf2f(m[2]) * v0[2] + bf2f(m[3]) * v0[3];
    acc += bf2f(m[4]) * v1[0] + bf2f(m[5]) * v1[1] + bf2f(m[6]) * v1[2] + bf2f(m[7]) * v1[3];
  }
  acc = wave_reduce_sum(acc);
  if (lane == 0) out[row] = scale / (acc + EPS_);
}

// loss = sum_ij u_i K_ij v_j c_ij with c = -REG*log(K) (exact inverse of build).
__global__ __launch_bounds__(256) void loss_kernel(const unsigned short* __restrict__ Km,
                                                   const float* __restrict__ u,
                                                   const float* __restrict__ v,
                                                   float* __restrict__ out) {
  const size_t NC = (size_t)N_B * N_B / 8;
  float acc = 0.f;
  for (size_t c = (size_t)blockIdx.x * 256 + threadIdx.x; c < NC; c += (size_t)gridDim.x * 256) {
    size_t e = c * 8;
    int i = (int)(e >> 12);
    int j = (int)(e & (N_B - 1));
    us8 m = *(const us8*)&Km[e];
    float ui = u[i];
#pragma unroll
    for (int t = 0; t < 8; ++t) {
      float kf = bf2f(m[t]);
      float cst = -REG_ * logf(kf);
      acc += ui * v[j + t] * kf * cst;
    }
  }
  acc = wave_reduce_sum(acc);
  __shared__ float wp[4];
  int wid = threadIdx.x >> 6, lane = threadIdx.x & 63;
  if (lane == 0) wp[wid] = acc;
  __syncthreads();
  if (threadIdx.x == 0) atomicAdd(out, wp[0] + wp[1] + wp[2] + wp[3]);
}

extern "C" void kernel_launch(void* const* d_in, const int* in_sizes, int n_in,
                              void* d_out, int out_size, void* d_ws, size_t ws_size,
                              hipStream_t stream) {
  const float* X = (const float*)d_in[0];
  const float* Y = (const float*)d_in[1];
  float* out = (float*)d_out;
  char* w = (char*)d_ws;

  const size_t MB = 1024 * 1024;
  unsigned short* Km  = (unsigned short*)w;
  unsigned short* KTm = (unsigned short*)(w + 32 * MB);
  unsigned short* Xe  = (unsigned short*)(w + 64 * MB);
  unsigned short* Ye  = (unsigned short*)(w + 64 * MB + (size_t)N_B * KE * 2);
  float* Xs = (float*)(w + 64 * MB + (size_t)2 * N_B * KE * 2);
  float* Ys = Xs + N_B;
  float* u  = Ys + N_B;
  float* v  = u + N_B;

  hipMemsetAsync(d_out, 0, sizeof(float), stream);

  prep_kernel<<<N_B * N_D / 256, 256, 0, stream>>>(X, Y, Xe, Ye);
  rownorm_kernel<<<N_B / 4, 256, 0, stream>>>(X, Xs);
  rownorm_kernel<<<N_B / 4, 256, 0, stream>>>(Y, Ys);
  init_v_kernel<<<N_B / 256, 256, 0, stream>>>(v);

  gemm_costK<<<dim3(32, 32), 256, 0, stream>>>(Xe, Ye, Xs, Ys, Km);
  transpose_bf16<<<dim3(64, 64), 256, 0, stream>>>(Km, KTm);

  const float inv_n = 1.0f / (float)N_B;
  for (int it = 0; it < 50; ++it) {
    matvec_bf16<<<N_B / 4, 256, 0, stream>>>(Km, v, u, inv_n);
    matvec_bf16<<<N_B / 4, 256, 0, stream>>>(KTm, u, v, inv_n);
  }

  loss_kernel<<<2048, 256, 0, stream>>>(Km, u, v, out);
}